// Round 7
// baseline (244.521 us; speedup 1.0000x reference)
//
#include <hip/hip_runtime.h>
#include <hip/hip_bf16.h>
#include <math.h>

#define B_   8
#define S_   2048
#define IN_  512
#define OUT_ 256
#define G_   8

// ws layout:
//  big path (ws >= 39 MiB):
//   [0,16MiB) y (pre-LN; LN fused into cosnk)  [16,32MiB) Xb  [32,32.5) Wb  [33,39) PTK
//  mid path (32.5 MiB <= ws < 39 MiB): PTK aliases Xb at 16 MiB, written after gemm
//  fallback (ws < 32.5 MiB): fp32 gemm, y [0,16), PTK [16,22)

typedef float  f32x4  __attribute__((ext_vector_type(4)));
typedef short  s16x8  __attribute__((ext_vector_type(8)));
typedef __bf16 bf16x8 __attribute__((ext_vector_type(8)));
typedef unsigned short u16x8 __attribute__((ext_vector_type(8)));

__device__ __forceinline__ float cos2pi(float f) {
#if __has_builtin(__builtin_amdgcn_cosf)
    return __builtin_amdgcn_cosf(f);   // v_cos_f32: revolutions (verified R1-R6)
#else
    return __cosf(6.28318530717958647692f * f);
#endif
}

__device__ __forceinline__ float fractf_(float f) {
#if __has_builtin(__builtin_amdgcn_fractf)
    return __builtin_amdgcn_fractf(f);
#else
    return f - floorf(f);
#endif
}

__device__ __forceinline__ unsigned short f2bf(float f) {
    unsigned u = __builtin_bit_cast(unsigned, f);
    u += 0x7fffu + ((u >> 16) & 1u);   // RNE; inputs finite
    return (unsigned short)(u >> 16);
}

// hardware f32 atomic add when available (global_atomic_add_f32); fallback atomicAdd
template <typename T>
__device__ __forceinline__ auto atomF_(T* p, T v, int) -> decltype(unsafeAtomicAdd(p, v)) {
    return unsafeAtomicAdd(p, v);
}
template <typename T>
__device__ __forceinline__ T atomF_(T* p, T v, long) {
    return atomicAdd(p, v);
}
__device__ __forceinline__ void atomAddF(float* p, float v) { atomF_(p, v, 0); }

// --- MFMA wrapper: tolerate either V8s(short) or V8y(__bf16) builtin signature ---
template <typename T>
__device__ __forceinline__ auto mfma_bf16_(T a, T b, f32x4 c, int)
    -> decltype(__builtin_amdgcn_mfma_f32_16x16x32_bf16(a, b, c, 0, 0, 0)) {
    return __builtin_amdgcn_mfma_f32_16x16x32_bf16(a, b, c, 0, 0, 0);
}
template <typename T>
__device__ __forceinline__ auto mfma_bf16_(T a, T b, f32x4 c, long)
    -> decltype(__builtin_amdgcn_mfma_f32_16x16x32_bf16(__builtin_bit_cast(bf16x8, a),
                                                        __builtin_bit_cast(bf16x8, b), c, 0, 0, 0)) {
    return __builtin_amdgcn_mfma_f32_16x16x32_bf16(__builtin_bit_cast(bf16x8, a),
                                                   __builtin_bit_cast(bf16x8, b), c, 0, 0, 0);
}
__device__ __forceinline__ f32x4 mfma_bf16(s16x8 a, s16x8 b, f32x4 c) {
    return mfma_bf16_(a, b, c, 0);
}

__device__ __forceinline__ void gld16(const void* g, void* l) {
    __builtin_amdgcn_global_load_lds((const __attribute__((address_space(1))) unsigned int*)g,
                                     (__attribute__((address_space(3))) unsigned int*)l,
                                     16, 0, 0);
}

// ---------------- device helper: prep one PTK record ----------------
__device__ __forceinline__ void prep_one(const float* __restrict__ P,
                                         const float* __restrict__ periods,
                                         float4* __restrict__ PTK, int tid) {
    const int j = tid >> 8, i = tid & 255;
    float p[8], iT[8], k2[8];
#pragma unroll
    for (int g = 0; g < 8; ++g) {
        const int idx = (i * 256 + j) * 8 + g;
        p[g]  = P[idx];
        iT[g] = 1.0f / periods[idx];
        k2[g] = 2.0f * cos2pi(iT[g]);
    }
    float4* base = PTK + (size_t)(j * 6) * 256 + i;
    base[0]    = make_float4(p[0], iT[0], p[1], iT[1]);
    base[256]  = make_float4(p[2], iT[2], p[3], iT[3]);
    base[512]  = make_float4(p[4], iT[4], p[5], iT[5]);
    base[768]  = make_float4(p[6], iT[6], p[7], iT[7]);
    base[1024] = make_float4(k2[0], k2[1], k2[2], k2[3]);
    base[1280] = make_float4(k2[4], k2[5], k2[6], k2[7]);
}

// ---------------- fused convert (x, W) + PTK prep: one launch ----------------
__global__ __launch_bounds__(256) void cvt_prep(const float* __restrict__ x,
                                                const float* __restrict__ M,
                                                const float* __restrict__ Wres,
                                                const float* __restrict__ P,
                                                const float* __restrict__ periods,
                                                unsigned short* __restrict__ Xb,
                                                unsigned short* __restrict__ Wb,
                                                float4* __restrict__ PTK) {
    const int bid = blockIdx.x;
    if (bid >= 4224) {                       // PTK prep: 256 blocks
        prep_one(P, periods, PTK, (bid - 4224) * 256 + threadIdx.x);
        return;
    }
    const float* src;
    unsigned short* dst;
    if (bid < 4096) {
        const int idx = bid * 256 + threadIdx.x;
        src = x + (size_t)idx * 8;
        dst = Xb + (size_t)idx * 8;
    } else {
        const int idx = (bid - 4096) * 256 + threadIdx.x;
        const int row = idx >> 6;
        const int col = (idx & 63) * 8;
        src = (row < 256) ? (M + (size_t)row * 512 + col)
                          : (Wres + (size_t)(row - 256) * 512 + col);
        dst = Wb + (size_t)row * 512 + col;
    }
    const float4 v0 = *(const float4*)(src);
    const float4 v1 = *(const float4*)(src + 4);
    u16x8 o;
    o[0] = f2bf(v0.x); o[1] = f2bf(v0.y); o[2] = f2bf(v0.z); o[3] = f2bf(v0.w);
    o[4] = f2bf(v1.x); o[5] = f2bf(v1.y); o[6] = f2bf(v1.z); o[7] = f2bf(v1.w);
    *(u16x8*)dst = o;
}

// standalone versions for the aliased / fallback paths
__global__ __launch_bounds__(256) void cvt_xw(const float* __restrict__ x,
                                              const float* __restrict__ M,
                                              const float* __restrict__ Wres,
                                              unsigned short* __restrict__ Xb,
                                              unsigned short* __restrict__ Wb) {
    const int bid = blockIdx.x;
    const float* src;
    unsigned short* dst;
    if (bid < 4096) {
        const int idx = bid * 256 + threadIdx.x;
        src = x + (size_t)idx * 8;
        dst = Xb + (size_t)idx * 8;
    } else {
        const int idx = (bid - 4096) * 256 + threadIdx.x;
        const int row = idx >> 6;
        const int col = (idx & 63) * 8;
        src = (row < 256) ? (M + (size_t)row * 512 + col)
                          : (Wres + (size_t)(row - 256) * 512 + col);
        dst = Wb + (size_t)row * 512 + col;
    }
    const float4 v0 = *(const float4*)(src);
    const float4 v1 = *(const float4*)(src + 4);
    u16x8 o;
    o[0] = f2bf(v0.x); o[1] = f2bf(v0.y); o[2] = f2bf(v0.z); o[3] = f2bf(v0.w);
    o[4] = f2bf(v1.x); o[5] = f2bf(v1.y); o[6] = f2bf(v1.z); o[7] = f2bf(v1.w);
    *(u16x8*)dst = o;
}

__global__ __launch_bounds__(256) void prep_ptk(const float* __restrict__ P,
                                                const float* __restrict__ periods,
                                                float4* __restrict__ PTK) {
    prep_one(P, periods, PTK, blockIdx.x * 256 + threadIdx.x);
}

// ---------------- bf16 MFMA GEMM: C[16384,512] = Xb * Wb^T (unchanged, proven R5/R6) ----------------
__global__ __launch_bounds__(256) void gemm_mfma(const unsigned short* __restrict__ Xb,
                                                 const unsigned short* __restrict__ Wb,
                                                 float* __restrict__ y,
                                                 float* __restrict__ out) {
    __shared__ __align__(16) unsigned short At[64 * 64];    // 8 KB
    __shared__ __align__(16) unsigned short Bt[128 * 64];   // 16 KB
    const int t    = threadIdx.x;
    const int col0 = blockIdx.x * 128;
    const int row0 = blockIdx.y * 64;

    const unsigned short* ga[2]; int la[2];
    const unsigned short* gb[4]; int lb[4];
#pragma unroll
    for (int cc = 0; cc < 2; ++cc) {
        const int L = cc * 256 + t;
        const int r = L >> 3;
        const int c = (L & 7) ^ (r & 7);
        ga[cc] = Xb + (size_t)(row0 + r) * 512 + c * 8;
        la[cc] = L * 8;
    }
#pragma unroll
    for (int cc = 0; cc < 4; ++cc) {
        const int L = cc * 256 + t;
        const int r = L >> 3;
        const int c = (L & 7) ^ (r & 7);
        gb[cc] = Wb + (size_t)(col0 + r) * 512 + c * 8;
        lb[cc] = L * 8;
    }

    const int lane = t & 63;
    const int wave = t >> 6;
    const int wn   = wave * 32;
    const int quad = lane >> 4;
    const int l16  = lane & 15;

    f32x4 acc[4][2];
#pragma unroll
    for (int mi = 0; mi < 4; ++mi)
#pragma unroll
        for (int ni = 0; ni < 2; ++ni) acc[mi][ni] = {0.0f, 0.0f, 0.0f, 0.0f};

    for (int k0 = 0; k0 < 512; k0 += 64) {
        __syncthreads();
#pragma unroll
        for (int cc = 0; cc < 2; ++cc) gld16(ga[cc] + k0, At + la[cc]);
#pragma unroll
        for (int cc = 0; cc < 4; ++cc) gld16(gb[cc] + k0, Bt + lb[cc]);
        __syncthreads();
#pragma unroll
        for (int ks = 0; ks < 2; ++ks) {
            const int cc = (ks * 4 + quad) ^ (l16 & 7);
            s16x8 af[4], bf[2];
#pragma unroll
            for (int mi = 0; mi < 4; ++mi) {
                const int ra = mi * 16 + l16;
                af[mi] = *(const s16x8*)(At + (ra * 8 + cc) * 8);
            }
#pragma unroll
            for (int ni = 0; ni < 2; ++ni) {
                const int rb = wn + ni * 16 + l16;
                bf[ni] = *(const s16x8*)(Bt + (rb * 8 + cc) * 8);
            }
#pragma unroll
            for (int mi = 0; mi < 4; ++mi)
#pragma unroll
                for (int ni = 0; ni < 2; ++ni)
                    acc[mi][ni] = mfma_bf16(af[mi], bf[ni], acc[mi][ni]);
        }
    }

    float* dst   = (col0 < 256) ? y : out;
    const int cb = (col0 & 255) + wn;
#pragma unroll
    for (int mi = 0; mi < 4; ++mi) {
        const int rbase = row0 + mi * 16 + quad * 4;
#pragma unroll
        for (int ni = 0; ni < 2; ++ni) {
            const int col = cb + ni * 16 + l16;
#pragma unroll
            for (int rg = 0; rg < 4; ++rg)
                dst[(size_t)(rbase + rg) * 256 + col] = acc[mi][ni][rg];
        }
    }
}

// ---------------- fallback fp32 GEMM (proven) ----------------
__global__ __launch_bounds__(256) void gemm_kernel(const float* __restrict__ x,
                                                   const float* __restrict__ M,
                                                   const float* __restrict__ Wres,
                                                   float* __restrict__ y,
                                                   float* __restrict__ out) {
    __shared__ float As[8][132];
    __shared__ float Bs[8][132];
    const int ct = blockIdx.x;
    const int rt = blockIdx.y;
    const int t  = threadIdx.x;
    const int row0 = rt * 128;
    const float* W = (ct < 2) ? M : Wres;
    const int wcol0 = (ct & 1) * 128;
    float acc[8][8];
#pragma unroll
    for (int r = 0; r < 8; ++r)
#pragma unroll
        for (int c = 0; c < 8; ++c) acc[r][c] = 0.0f;
    const int lr = t >> 1;
    const int lk = (t & 1) << 2;
    for (int k0 = 0; k0 < 512; k0 += 8) {
        float4 av = *(const float4*)(x + (size_t)(row0 + lr) * 512 + k0 + lk);
        float4 bv = *(const float4*)(W + (size_t)(wcol0 + lr) * 512 + k0 + lk);
        __syncthreads();
        As[lk + 0][lr] = av.x; As[lk + 1][lr] = av.y; As[lk + 2][lr] = av.z; As[lk + 3][lr] = av.w;
        Bs[lk + 0][lr] = bv.x; Bs[lk + 1][lr] = bv.y; Bs[lk + 2][lr] = bv.z; Bs[lk + 3][lr] = bv.w;
        __syncthreads();
        const int tx = t & 15, ty = t >> 4;
#pragma unroll
        for (int kk = 0; kk < 8; ++kk) {
            const float4 a0 = *(const float4*)&As[kk][ty * 8];
            const float4 a1 = *(const float4*)&As[kk][ty * 8 + 4];
            const float4 b0 = *(const float4*)&Bs[kk][tx * 8];
            const float4 b1 = *(const float4*)&Bs[kk][tx * 8 + 4];
            const float ar[8] = {a0.x, a0.y, a0.z, a0.w, a1.x, a1.y, a1.z, a1.w};
            const float br[8] = {b0.x, b0.y, b0.z, b0.w, b1.x, b1.y, b1.z, b1.w};
#pragma unroll
            for (int r = 0; r < 8; ++r)
#pragma unroll
                for (int c = 0; c < 8; ++c) acc[r][c] = fmaf(ar[r], br[c], acc[r][c]);
        }
    }
    const int tx = t & 15, ty = t >> 4;
    float* dst = (ct < 2) ? y : out;
    const int cbase = (ct & 1) * 128 + tx * 8;
#pragma unroll
    for (int r = 0; r < 8; ++r) {
        float4 v0 = {acc[r][0], acc[r][1], acc[r][2], acc[r][3]};
        float4 v1 = {acc[r][4], acc[r][5], acc[r][6], acc[r][7]};
        float* p = dst + (size_t)(row0 + ty * 8 + r) * 256 + cbase;
        *(float4*)(p)     = v0;
        *(float4*)(p + 4) = v1;
    }
}

// ---------------- fused LN + A-gen + contraction (R6 core, LN in staging) ----------------
// grid 1024: block = 8 s x 128 i (i-half) x 128 j (j-half); threads 128 i x 2 jq.
// Staging threads read the FULL 256-j row of pre-LN y, compute row mean/var
// (shfl-reduced across the 4 threads per slot), apply LN, store this block's
// 128-j half to LDS. Main loop + atomic epilogue identical to R6's cosnk_js.
__global__ __launch_bounds__(256, 4) void cosnk_lnjs(const float4* __restrict__ PTK,
                                                     const float* __restrict__ ypre,
                                                     const float* __restrict__ ln_scale,
                                                     const float* __restrict__ ln_bias,
                                                     float* __restrict__ out) {
    __shared__ float xs[128 * 64];   // [j_local][slot=s*8+b], 32 KB; reused for reduce
    const int t  = threadIdx.x;
    const int bx = blockIdx.x;
    const int ih = (bx >> 2) & 1;                  // XCD-pinned i-half
    const int rid = ((bx >> 3) << 2) | (bx & 3);   // 0..511
    const int stile = rid >> 1;                    // 0..255
    const int jh = rid & 1;
    const int s0 = stile * 8;
    const int jbase = jh * 128;

    {   // stage with fused LayerNorm
        const int slot = t >> 2;        // 0..63 = st*8+b
        const int st   = slot >> 3;
        const int b    = slot & 7;
        const int jg   = t & 3;         // 64-j group over the FULL 256 row
        const float* src = ypre + (size_t)(b * S_ + s0 + st) * 256 + jg * 64;
        float4 v[16];
        float sum = 0.0f, ssq = 0.0f;
#pragma unroll
        for (int q = 0; q < 16; ++q) {
            v[q] = *(const float4*)(src + 4 * q);
            sum += v[q].x + v[q].y + v[q].z + v[q].w;
            ssq += v[q].x * v[q].x + v[q].y * v[q].y + v[q].z * v[q].z + v[q].w * v[q].w;
        }
        // combine across the 4 threads of this slot (adjacent lanes in one wave)
        sum += __shfl_xor(sum, 1); sum += __shfl_xor(sum, 2);
        ssq += __shfl_xor(ssq, 1); ssq += __shfl_xor(ssq, 2);
        const float mu  = sum * (1.0f / 256.0f);
        const float var = ssq * (1.0f / 256.0f) - mu * mu;
        const float rs  = rsqrtf(var + 1e-5f);
        if ((jg >> 1) == jh) {          // this thread's span lies in our j-half
            const int jl0s = (jg & 1) * 64;
#pragma unroll
            for (int q = 0; q < 16; ++q) {
                const float4 sc = *(const float4*)(ln_scale + jg * 64 + 4 * q);
                const float4 bi = *(const float4*)(ln_bias  + jg * 64 + 4 * q);
                const int jl = jl0s + 4 * q;
                xs[(jl + 0) * 64 + slot] = (v[q].x - mu) * rs * sc.x + bi.x;
                xs[(jl + 1) * 64 + slot] = (v[q].y - mu) * rs * sc.y + bi.y;
                xs[(jl + 2) * 64 + slot] = (v[q].z - mu) * rs * sc.z + bi.z;
                xs[(jl + 3) * 64 + slot] = (v[q].w - mu) * rs * sc.w + bi.w;
            }
        }
    }
    __syncthreads();

    const int i   = ih * 128 + (t & 127);
    const int jq  = t >> 7;             // 0 or 1: 64-j quarter
    const int jl0 = jq * 64;
    const float sv0 = (float)s0;

    float acc[8][8];
#pragma unroll
    for (int s = 0; s < 8; ++s)
#pragma unroll
        for (int b = 0; b < 8; ++b) acc[s][b] = 0.0f;

    const float4* ptk = PTK + (size_t)(jbase + jl0) * 1536 + i;
    float4 q0 = ptk[0],    q1 = ptk[256],  q2 = ptk[512];
    float4 q3 = ptk[768], k01 = ptk[1024], k23 = ptk[1280];

#define CHEB8(p_, iT_, k2_)                         \
    do {                                            \
        float f0 = fractf_(sv0 * (iT_));            \
        float c0 = cos2pi(f0);                      \
        float c1 = cos2pi(fractf_(f0 + (iT_)));     \
        float c2 = fmaf((k2_), c1, -c0);            \
        float c3 = fmaf((k2_), c2, -c1);            \
        float c4 = fmaf((k2_), c3, -c2);            \
        float c5 = fmaf((k2_), c4, -c3);            \
        float c6 = fmaf((k2_), c5, -c4);            \
        float c7 = fmaf((k2_), c6, -c5);            \
        a0 = fmaf((p_), c0, a0); a1 = fmaf((p_), c1, a1); \
        a2 = fmaf((p_), c2, a2); a3 = fmaf((p_), c3, a3); \
        a4 = fmaf((p_), c4, a4); a5 = fmaf((p_), c5, a5); \
        a6 = fmaf((p_), c6, a6); a7 = fmaf((p_), c7, a7); \
    } while (0)

    for (int jj = 0; jj < 64; ++jj) {
        const float4* pn = ptk + ((jj < 63) ? 1536 : 0);   // next-j prefetch
        const float4 n0 = pn[0],   n1 = pn[256],  n2 = pn[512];
        const float4 n3 = pn[768], n4 = pn[1024], n5 = pn[1280];

        float a0 = 0.f, a1 = 0.f, a2 = 0.f, a3 = 0.f, a4 = 0.f, a5 = 0.f, a6 = 0.f, a7 = 0.f;
        CHEB8(q0.x, q0.y, k01.x);
        CHEB8(q0.z, q0.w, k01.y);
        CHEB8(q1.x, q1.y, k01.z);
        CHEB8(q1.z, q1.w, k01.w);
        CHEB8(q2.x, q2.y, k23.x);
        CHEB8(q2.z, q2.w, k23.y);
        CHEB8(q3.x, q3.y, k23.z);
        CHEB8(q3.z, q3.w, k23.w);

        const float* xrow = &xs[(jl0 + jj) * 64];   // wave-uniform -> LDS broadcast
        const float as_[8] = {a0, a1, a2, a3, a4, a5, a6, a7};
#pragma unroll
        for (int s = 0; s < 8; ++s) {
            const float4 xa = *(const float4*)(xrow + s * 8);
            const float4 xb = *(const float4*)(xrow + s * 8 + 4);
            acc[s][0] = fmaf(as_[s], xa.x, acc[s][0]);
            acc[s][1] = fmaf(as_[s], xa.y, acc[s][1]);
            acc[s][2] = fmaf(as_[s], xa.z, acc[s][2]);
            acc[s][3] = fmaf(as_[s], xa.w, acc[s][3]);
            acc[s][4] = fmaf(as_[s], xb.x, acc[s][4]);
            acc[s][5] = fmaf(as_[s], xb.y, acc[s][5]);
            acc[s][6] = fmaf(as_[s], xb.z, acc[s][6]);
            acc[s][7] = fmaf(as_[s], xb.w, acc[s][7]);
        }
        q0 = n0; q1 = n1; q2 = n2; q3 = n3; k01 = n4; k23 = n5;
        ptk = pn;
    }
#undef CHEB8

    // intra-block jq-reduce, then device-scope atomic add (2 blocks per element)
    __syncthreads();
    const int tl = t & 127;
    if (jq) {
#pragma unroll
        for (int slot = 0; slot < 64; ++slot)
            xs[slot * 128 + tl] = acc[slot >> 3][slot & 7];
    }
    __syncthreads();
    if (!jq) {
#pragma unroll
        for (int slot = 0; slot < 64; ++slot) {
            const int st = slot >> 3, b = slot & 7;
            const float v = acc[st][b] + xs[slot * 128 + tl];
            atomAddF(&out[(size_t)(b * S_ + s0 + st) * 256 + i], v);
        }
    }
}

extern "C" void kernel_launch(void* const* d_in, const int* in_sizes, int n_in,
                              void* d_out, int out_size, void* d_ws, size_t ws_size,
                              hipStream_t stream) {
    const float* x        = (const float*)d_in[0];
    const float* M        = (const float*)d_in[1];
    const float* P        = (const float*)d_in[2];
    const float* Wres     = (const float*)d_in[3];
    const float* ln_scale = (const float*)d_in[4];
    const float* ln_bias  = (const float*)d_in[5];
    const float* periods  = (const float*)d_in[6];

    float* out = (float*)d_out;
    char*  wsb = (char*)d_ws;
    const size_t MB = 1024 * 1024;
    float* y = (float*)wsb;                                     // 16 MiB
    unsigned short* Xb = (unsigned short*)(wsb + 16 * MB);      // 16 MiB
    unsigned short* Wb = (unsigned short*)(wsb + 32 * MB);      // 0.5 MiB

    const bool big  = (ws_size >= 39 * MB);        // un-aliased PTK at 33 MiB
    const bool mfma = (ws_size >= (size_t)34078720);

    float4* PTK;
    if (big) {
        PTK = (float4*)(wsb + 33 * MB);
        cvt_prep<<<4480, 256, 0, stream>>>(x, M, Wres, P, periods, Xb, Wb, PTK);
        dim3 ggrid(4, 256);
        gemm_mfma<<<ggrid, 256, 0, stream>>>(Xb, Wb, y, out);
    } else if (mfma) {
        PTK = (float4*)(wsb + 16 * MB);            // aliases Xb; written after gemm
        cvt_xw<<<4224, 256, 0, stream>>>(x, M, Wres, Xb, Wb);
        dim3 ggrid(4, 256);
        gemm_mfma<<<ggrid, 256, 0, stream>>>(Xb, Wb, y, out);
        prep_ptk<<<256, 256, 0, stream>>>(P, periods, PTK);
    } else {
        PTK = (float4*)(wsb + 16 * MB);
        dim3 ggrid(4, 128);
        gemm_kernel<<<ggrid, 256, 0, stream>>>(x, M, Wres, y, out);
        prep_ptk<<<256, 256, 0, stream>>>(P, periods, PTK);
    }

    cosnk_lnjs<<<1024, 256, 0, stream>>>(PTK, y, ln_scale, ln_bias, out);
}

// Round 8
// 234.398 us; speedup vs baseline: 1.0432x; 1.0432x over previous
//
#include <hip/hip_runtime.h>
#include <hip/hip_bf16.h>
#include <math.h>

#define B_   8
#define S_   2048
#define IN_  512
#define OUT_ 256
#define G_   8

// ws layout:
//  big path (ws >= 39 MiB):
//   [0,16MiB) y  [16,32MiB) Xb  [32,32.5) Wb  [33,39) PTK (un-aliased)
//  mid path (32.5 <= ws < 39 MiB): PTK aliases Xb at 16 MiB, written after gemm
//  fallback (ws < 32.5 MiB): fp32 gemm, y [0,16), PTK [16,22)
// PTK layout (R8): per j, 6 float4-quads x 256 i:
//   quad0 p[0..3] | quad1 p[4..7] | quad2 iT[0..3] | quad3 iT[4..7] | quad4 2cos(2pi iT)[0..3] | quad5 [4..7]

typedef float  f32x2  __attribute__((ext_vector_type(2)));
typedef float  f32x4  __attribute__((ext_vector_type(4)));
typedef short  s16x8  __attribute__((ext_vector_type(8)));
typedef __bf16 bf16x8 __attribute__((ext_vector_type(8)));
typedef unsigned short u16x8 __attribute__((ext_vector_type(8)));

__device__ __forceinline__ float cos2pi(float f) {
#if __has_builtin(__builtin_amdgcn_cosf)
    return __builtin_amdgcn_cosf(f);   // v_cos_f32: revolutions (verified R1-R7)
#else
    return __cosf(6.28318530717958647692f * f);
#endif
}

__device__ __forceinline__ float fractf_(float f) {
#if __has_builtin(__builtin_amdgcn_fractf)
    return __builtin_amdgcn_fractf(f);
#else
    return f - floorf(f);
#endif
}

__device__ __forceinline__ unsigned short f2bf(float f) {
    unsigned u = __builtin_bit_cast(unsigned, f);
    u += 0x7fffu + ((u >> 16) & 1u);   // RNE; inputs finite
    return (unsigned short)(u >> 16);
}

// hardware f32 atomic add when available; fallback atomicAdd
template <typename T>
__device__ __forceinline__ auto atomF_(T* p, T v, int) -> decltype(unsafeAtomicAdd(p, v)) {
    return unsafeAtomicAdd(p, v);
}
template <typename T>
__device__ __forceinline__ T atomF_(T* p, T v, long) {
    return atomicAdd(p, v);
}
__device__ __forceinline__ void atomAddF(float* p, float v) { atomF_(p, v, 0); }

// --- MFMA wrapper: tolerate either V8s(short) or V8y(__bf16) builtin signature ---
template <typename T>
__device__ __forceinline__ auto mfma_bf16_(T a, T b, f32x4 c, int)
    -> decltype(__builtin_amdgcn_mfma_f32_16x16x32_bf16(a, b, c, 0, 0, 0)) {
    return __builtin_amdgcn_mfma_f32_16x16x32_bf16(a, b, c, 0, 0, 0);
}
template <typename T>
__device__ __forceinline__ auto mfma_bf16_(T a, T b, f32x4 c, long)
    -> decltype(__builtin_amdgcn_mfma_f32_16x16x32_bf16(__builtin_bit_cast(bf16x8, a),
                                                        __builtin_bit_cast(bf16x8, b), c, 0, 0, 0)) {
    return __builtin_amdgcn_mfma_f32_16x16x32_bf16(__builtin_bit_cast(bf16x8, a),
                                                   __builtin_bit_cast(bf16x8, b), c, 0, 0, 0);
}
__device__ __forceinline__ f32x4 mfma_bf16(s16x8 a, s16x8 b, f32x4 c) {
    return mfma_bf16_(a, b, c, 0);
}

__device__ __forceinline__ void gld16(const void* g, void* l) {
    __builtin_amdgcn_global_load_lds((const __attribute__((address_space(1))) unsigned int*)g,
                                     (__attribute__((address_space(3))) unsigned int*)l,
                                     16, 0, 0);
}

__device__ __forceinline__ f32x2 lo2(float4 v) { f32x2 r; r.x = v.x; r.y = v.y; return r; }
__device__ __forceinline__ f32x2 hi2(float4 v) { f32x2 r; r.x = v.z; r.y = v.w; return r; }

// ---------------- device helper: prep one PTK record (pair-friendly layout) ----------------
__device__ __forceinline__ void prep_one(const float* __restrict__ P,
                                         const float* __restrict__ periods,
                                         float4* __restrict__ PTK, int tid) {
    const int j = tid >> 8, i = tid & 255;
    float p[8], iT[8], k2[8];
#pragma unroll
    for (int g = 0; g < 8; ++g) {
        const int idx = (i * 256 + j) * 8 + g;
        p[g]  = P[idx];
        iT[g] = 1.0f / periods[idx];
        k2[g] = 2.0f * cos2pi(iT[g]);
    }
    float4* base = PTK + (size_t)(j * 6) * 256 + i;
    base[0]    = make_float4(p[0],  p[1],  p[2],  p[3]);
    base[256]  = make_float4(p[4],  p[5],  p[6],  p[7]);
    base[512]  = make_float4(iT[0], iT[1], iT[2], iT[3]);
    base[768]  = make_float4(iT[4], iT[5], iT[6], iT[7]);
    base[1024] = make_float4(k2[0], k2[1], k2[2], k2[3]);
    base[1280] = make_float4(k2[4], k2[5], k2[6], k2[7]);
}

// ---------------- fused convert (x, W) + PTK prep: one launch (big path) ----------------
__global__ __launch_bounds__(256) void cvt_prep(const float* __restrict__ x,
                                                const float* __restrict__ M,
                                                const float* __restrict__ Wres,
                                                const float* __restrict__ P,
                                                const float* __restrict__ periods,
                                                unsigned short* __restrict__ Xb,
                                                unsigned short* __restrict__ Wb,
                                                float4* __restrict__ PTK) {
    const int bid = blockIdx.x;
    if (bid >= 4224) {                       // PTK prep: 256 blocks
        prep_one(P, periods, PTK, (bid - 4224) * 256 + threadIdx.x);
        return;
    }
    const float* src;
    unsigned short* dst;
    if (bid < 4096) {
        const int idx = bid * 256 + threadIdx.x;
        src = x + (size_t)idx * 8;
        dst = Xb + (size_t)idx * 8;
    } else {
        const int idx = (bid - 4096) * 256 + threadIdx.x;
        const int row = idx >> 6;
        const int col = (idx & 63) * 8;
        src = (row < 256) ? (M + (size_t)row * 512 + col)
                          : (Wres + (size_t)(row - 256) * 512 + col);
        dst = Wb + (size_t)row * 512 + col;
    }
    const float4 v0 = *(const float4*)(src);
    const float4 v1 = *(const float4*)(src + 4);
    u16x8 o;
    o[0] = f2bf(v0.x); o[1] = f2bf(v0.y); o[2] = f2bf(v0.z); o[3] = f2bf(v0.w);
    o[4] = f2bf(v1.x); o[5] = f2bf(v1.y); o[6] = f2bf(v1.z); o[7] = f2bf(v1.w);
    *(u16x8*)dst = o;
}

// standalone versions for the aliased / fallback paths
__global__ __launch_bounds__(256) void cvt_xw(const float* __restrict__ x,
                                              const float* __restrict__ M,
                                              const float* __restrict__ Wres,
                                              unsigned short* __restrict__ Xb,
                                              unsigned short* __restrict__ Wb) {
    const int bid = blockIdx.x;
    const float* src;
    unsigned short* dst;
    if (bid < 4096) {
        const int idx = bid * 256 + threadIdx.x;
        src = x + (size_t)idx * 8;
        dst = Xb + (size_t)idx * 8;
    } else {
        const int idx = (bid - 4096) * 256 + threadIdx.x;
        const int row = idx >> 6;
        const int col = (idx & 63) * 8;
        src = (row < 256) ? (M + (size_t)row * 512 + col)
                          : (Wres + (size_t)(row - 256) * 512 + col);
        dst = Wb + (size_t)row * 512 + col;
    }
    const float4 v0 = *(const float4*)(src);
    const float4 v1 = *(const float4*)(src + 4);
    u16x8 o;
    o[0] = f2bf(v0.x); o[1] = f2bf(v0.y); o[2] = f2bf(v0.z); o[3] = f2bf(v0.w);
    o[4] = f2bf(v1.x); o[5] = f2bf(v1.y); o[6] = f2bf(v1.z); o[7] = f2bf(v1.w);
    *(u16x8*)dst = o;
}

__global__ __launch_bounds__(256) void prep_ptk(const float* __restrict__ P,
                                                const float* __restrict__ periods,
                                                float4* __restrict__ PTK) {
    prep_one(P, periods, PTK, blockIdx.x * 256 + threadIdx.x);
}

// ---------------- bf16 MFMA GEMM: C[16384,512] = Xb * Wb^T (unchanged, proven R5-R7) ----------------
__global__ __launch_bounds__(256) void gemm_mfma(const unsigned short* __restrict__ Xb,
                                                 const unsigned short* __restrict__ Wb,
                                                 float* __restrict__ y,
                                                 float* __restrict__ out) {
    __shared__ __align__(16) unsigned short At[64 * 64];    // 8 KB
    __shared__ __align__(16) unsigned short Bt[128 * 64];   // 16 KB
    const int t    = threadIdx.x;
    const int col0 = blockIdx.x * 128;
    const int row0 = blockIdx.y * 64;

    const unsigned short* ga[2]; int la[2];
    const unsigned short* gb[4]; int lb[4];
#pragma unroll
    for (int cc = 0; cc < 2; ++cc) {
        const int L = cc * 256 + t;
        const int r = L >> 3;
        const int c = (L & 7) ^ (r & 7);
        ga[cc] = Xb + (size_t)(row0 + r) * 512 + c * 8;
        la[cc] = L * 8;
    }
#pragma unroll
    for (int cc = 0; cc < 4; ++cc) {
        const int L = cc * 256 + t;
        const int r = L >> 3;
        const int c = (L & 7) ^ (r & 7);
        gb[cc] = Wb + (size_t)(col0 + r) * 512 + c * 8;
        lb[cc] = L * 8;
    }

    const int lane = t & 63;
    const int wave = t >> 6;
    const int wn   = wave * 32;
    const int quad = lane >> 4;
    const int l16  = lane & 15;

    f32x4 acc[4][2];
#pragma unroll
    for (int mi = 0; mi < 4; ++mi)
#pragma unroll
        for (int ni = 0; ni < 2; ++ni) acc[mi][ni] = {0.0f, 0.0f, 0.0f, 0.0f};

    for (int k0 = 0; k0 < 512; k0 += 64) {
        __syncthreads();
#pragma unroll
        for (int cc = 0; cc < 2; ++cc) gld16(ga[cc] + k0, At + la[cc]);
#pragma unroll
        for (int cc = 0; cc < 4; ++cc) gld16(gb[cc] + k0, Bt + lb[cc]);
        __syncthreads();
#pragma unroll
        for (int ks = 0; ks < 2; ++ks) {
            const int cc = (ks * 4 + quad) ^ (l16 & 7);
            s16x8 af[4], bf[2];
#pragma unroll
            for (int mi = 0; mi < 4; ++mi) {
                const int ra = mi * 16 + l16;
                af[mi] = *(const s16x8*)(At + (ra * 8 + cc) * 8);
            }
#pragma unroll
            for (int ni = 0; ni < 2; ++ni) {
                const int rb = wn + ni * 16 + l16;
                bf[ni] = *(const s16x8*)(Bt + (rb * 8 + cc) * 8);
            }
#pragma unroll
            for (int mi = 0; mi < 4; ++mi)
#pragma unroll
                for (int ni = 0; ni < 2; ++ni)
                    acc[mi][ni] = mfma_bf16(af[mi], bf[ni], acc[mi][ni]);
        }
    }

    float* dst   = (col0 < 256) ? y : out;
    const int cb = (col0 & 255) + wn;
#pragma unroll
    for (int mi = 0; mi < 4; ++mi) {
        const int rbase = row0 + mi * 16 + quad * 4;
#pragma unroll
        for (int ni = 0; ni < 2; ++ni) {
            const int col = cb + ni * 16 + l16;
#pragma unroll
            for (int rg = 0; rg < 4; ++rg)
                dst[(size_t)(rbase + rg) * 256 + col] = acc[mi][ni][rg];
        }
    }
}

// ---------------- fallback fp32 GEMM (proven) ----------------
__global__ __launch_bounds__(256) void gemm_kernel(const float* __restrict__ x,
                                                   const float* __restrict__ M,
                                                   const float* __restrict__ Wres,
                                                   float* __restrict__ y,
                                                   float* __restrict__ out) {
    __shared__ float As[8][132];
    __shared__ float Bs[8][132];
    const int ct = blockIdx.x;
    const int rt = blockIdx.y;
    const int t  = threadIdx.x;
    const int row0 = rt * 128;
    const float* W = (ct < 2) ? M : Wres;
    const int wcol0 = (ct & 1) * 128;
    float acc[8][8];
#pragma unroll
    for (int r = 0; r < 8; ++r)
#pragma unroll
        for (int c = 0; c < 8; ++c) acc[r][c] = 0.0f;
    const int lr = t >> 1;
    const int lk = (t & 1) << 2;
    for (int k0 = 0; k0 < 512; k0 += 8) {
        float4 av = *(const float4*)(x + (size_t)(row0 + lr) * 512 + k0 + lk);
        float4 bv = *(const float4*)(W + (size_t)(wcol0 + lr) * 512 + k0 + lk);
        __syncthreads();
        As[lk + 0][lr] = av.x; As[lk + 1][lr] = av.y; As[lk + 2][lr] = av.z; As[lk + 3][lr] = av.w;
        Bs[lk + 0][lr] = bv.x; Bs[lk + 1][lr] = bv.y; Bs[lk + 2][lr] = bv.z; Bs[lk + 3][lr] = bv.w;
        __syncthreads();
        const int tx = t & 15, ty = t >> 4;
#pragma unroll
        for (int kk = 0; kk < 8; ++kk) {
            const float4 a0 = *(const float4*)&As[kk][ty * 8];
            const float4 a1 = *(const float4*)&As[kk][ty * 8 + 4];
            const float4 b0 = *(const float4*)&Bs[kk][tx * 8];
            const float4 b1 = *(const float4*)&Bs[kk][tx * 8 + 4];
            const float ar[8] = {a0.x, a0.y, a0.z, a0.w, a1.x, a1.y, a1.z, a1.w};
            const float br[8] = {b0.x, b0.y, b0.z, b0.w, b1.x, b1.y, b1.z, b1.w};
#pragma unroll
            for (int r = 0; r < 8; ++r)
#pragma unroll
                for (int c = 0; c < 8; ++c) acc[r][c] = fmaf(ar[r], br[c], acc[r][c]);
        }
    }
    const int tx = t & 15, ty = t >> 4;
    float* dst = (ct < 2) ? y : out;
    const int cbase = (ct & 1) * 128 + tx * 8;
#pragma unroll
    for (int r = 0; r < 8; ++r) {
        float4 v0 = {acc[r][0], acc[r][1], acc[r][2], acc[r][3]};
        float4 v1 = {acc[r][4], acc[r][5], acc[r][6], acc[r][7]};
        float* p = dst + (size_t)(row0 + ty * 8 + r) * 256 + cbase;
        *(float4*)(p)     = v0;
        *(float4*)(p + 4) = v1;
    }
}

// ---------------- LayerNorm (in-place; restored from R6 — fusion measured -8 net in R7) ----------------
__global__ __launch_bounds__(256) void ln_kernel(float* __restrict__ y,
                                                 const float* __restrict__ scale,
                                                 const float* __restrict__ bias) {
    const int t    = threadIdx.x;
    const int row  = blockIdx.x * 4 + (t >> 6);
    const int lane = t & 63;
    float* p = y + (size_t)row * 256 + lane * 4;
    float4 v = *(float4*)p;
    float s  = v.x + v.y + v.z + v.w;
    float ss = v.x * v.x + v.y * v.y + v.z * v.z + v.w * v.w;
#pragma unroll
    for (int off = 32; off > 0; off >>= 1) {
        s  += __shfl_xor(s, off);
        ss += __shfl_xor(ss, off);
    }
    const float mu  = s * (1.0f / 256.0f);
    const float var = ss * (1.0f / 256.0f) - mu * mu;
    const float rs  = rsqrtf(var + 1e-5f);
    float4 sc = *(const float4*)(scale + lane * 4);
    float4 bi = *(const float4*)(bias + lane * 4);
    float4 o;
    o.x = (v.x - mu) * rs * sc.x + bi.x;
    o.y = (v.y - mu) * rs * sc.y + bi.y;
    o.z = (v.z - mu) * rs * sc.z + bi.z;
    o.w = (v.w - mu) * rs * sc.w + bi.w;
    *(float4*)p = o;
}

// ---------------- fused A-gen + contraction: R6 structure + packed-f32 math ----------------
// grid 1024: block = 8 s x 128 i (i-half) x 128 j (j-half); threads 128 i x 2 jq.
// Chebyshev recurrences packed over g-pairs (f32x2 -> v_pk_fma_f32); b-accumulation
// packed over b-pairs. cos/fract remain scalar (transcendental pipe).
__global__ __launch_bounds__(256, 4) void cosnk_pk(const float4* __restrict__ PTK,
                                                   const float* __restrict__ xt,
                                                   float* __restrict__ out) {
    __shared__ float xs[128 * 64];   // [j_local][slot=s*8+b], 32 KB; reused for reduce
    const int t  = threadIdx.x;
    const int bx = blockIdx.x;
    const int ih = (bx >> 2) & 1;                  // XCD-pinned i-half
    const int rid = ((bx >> 3) << 2) | (bx & 3);   // 0..511
    const int stile = rid >> 1;                    // 0..255
    const int jh = rid & 1;
    const int s0 = stile * 8;
    const int jbase = jh * 128;

    {   // stage x_t[b][s0+st][jbase..+128] -> xs[j_local][slot]
        const int slot = t >> 2;        // 0..63 = st*8+b
        const int st   = slot >> 3;
        const int b    = slot & 7;
        const int jg   = t & 3;         // 32-j group
        const float* src = xt + (size_t)(b * S_ + s0 + st) * 256 + jbase + jg * 32;
#pragma unroll
        for (int q = 0; q < 8; ++q) {
            float4 v = *(const float4*)(src + 4 * q);
            const int jl = jg * 32 + 4 * q;
            xs[(jl + 0) * 64 + slot] = v.x;
            xs[(jl + 1) * 64 + slot] = v.y;
            xs[(jl + 2) * 64 + slot] = v.z;
            xs[(jl + 3) * 64 + slot] = v.w;
        }
    }
    __syncthreads();

    const int i   = ih * 128 + (t & 127);
    const int jq  = t >> 7;             // 0 or 1: 64-j quarter
    const int jl0 = jq * 64;
    const float sv0 = (float)s0;
    f32x2 sv0v; sv0v.x = sv0; sv0v.y = sv0;

    f32x2 accP[8][4];                   // [s][b-pair]
#pragma unroll
    for (int s = 0; s < 8; ++s)
#pragma unroll
        for (int q = 0; q < 4; ++q) { accP[s][q].x = 0.0f; accP[s][q].y = 0.0f; }

    const float4* ptk = PTK + (size_t)(jbase + jl0) * 1536 + i;
    float4 qp0 = ptk[0],    qp1 = ptk[256];   // p pairs
    float4 qt0 = ptk[512],  qt1 = ptk[768];   // iT pairs
    float4 qk0 = ptk[1024], qk1 = ptk[1280];  // 2cos(2pi iT) pairs

#define CHEBP(p2_, t2_, k2_)                                \
    do {                                                    \
        f32x2 f0 = sv0v * (t2_);                            \
        f0.x = fractf_(f0.x); f0.y = fractf_(f0.y);         \
        f32x2 c0; c0.x = cos2pi(f0.x); c0.y = cos2pi(f0.y); \
        f32x2 f1 = f0 + (t2_);                              \
        f1.x = fractf_(f1.x); f1.y = fractf_(f1.y);         \
        f32x2 c1; c1.x = cos2pi(f1.x); c1.y = cos2pi(f1.y); \
        f32x2 c2 = (k2_) * c1 - c0;                         \
        f32x2 c3 = (k2_) * c2 - c1;                         \
        f32x2 c4 = (k2_) * c3 - c2;                         \
        f32x2 c5 = (k2_) * c4 - c3;                         \
        f32x2 c6 = (k2_) * c5 - c4;                         \
        f32x2 c7 = (k2_) * c6 - c5;                         \
        A0 += (p2_) * c0; A1 += (p2_) * c1;                 \
        A2 += (p2_) * c2; A3 += (p2_) * c3;                 \
        A4 += (p2_) * c4; A5 += (p2_) * c5;                 \
        A6 += (p2_) * c6; A7 += (p2_) * c7;                 \
    } while (0)

    for (int jj = 0; jj < 64; ++jj) {
        const float4* pn = ptk + ((jj < 63) ? 1536 : 0);   // next-j prefetch
        const float4 n0 = pn[0],   n1 = pn[256],  n2 = pn[512];
        const float4 n3 = pn[768], n4 = pn[1024], n5 = pn[1280];

        f32x2 A0 = {0.f, 0.f}, A1 = {0.f, 0.f}, A2 = {0.f, 0.f}, A3 = {0.f, 0.f};
        f32x2 A4 = {0.f, 0.f}, A5 = {0.f, 0.f}, A6 = {0.f, 0.f}, A7 = {0.f, 0.f};
        CHEBP(lo2(qp0), lo2(qt0), lo2(qk0));   // g0,g1
        CHEBP(hi2(qp0), hi2(qt0), hi2(qk0));   // g2,g3
        CHEBP(lo2(qp1), lo2(qt1), lo2(qk1));   // g4,g5
        CHEBP(hi2(qp1), hi2(qt1), hi2(qk1));   // g6,g7

        const float as_[8] = {A0.x + A0.y, A1.x + A1.y, A2.x + A2.y, A3.x + A3.y,
                              A4.x + A4.y, A5.x + A5.y, A6.x + A6.y, A7.x + A7.y};

        const float* xrow = &xs[(jl0 + jj) * 64];   // wave-uniform -> LDS broadcast
#pragma unroll
        for (int s = 0; s < 8; ++s) {
            const float4 xa = *(const float4*)(xrow + s * 8);
            const float4 xb = *(const float4*)(xrow + s * 8 + 4);
            f32x2 av; av.x = as_[s]; av.y = as_[s];
            accP[s][0] += av * lo2(xa);
            accP[s][1] += av * hi2(xa);
            accP[s][2] += av * lo2(xb);
            accP[s][3] += av * hi2(xb);
        }
        qp0 = n0; qp1 = n1; qt0 = n2; qt1 = n3; qk0 = n4; qk1 = n5;
        ptk = pn;
    }
#undef CHEBP

    // intra-block jq-reduce, then device-scope atomic add (2 blocks per element)
    __syncthreads();
    const int tl = t & 127;
    if (jq) {
#pragma unroll
        for (int slot = 0; slot < 64; ++slot) {
            const int st = slot >> 3, b = slot & 7;
            xs[slot * 128 + tl] = accP[st][b >> 1][b & 1];
        }
    }
    __syncthreads();
    if (!jq) {
#pragma unroll
        for (int slot = 0; slot < 64; ++slot) {
            const int st = slot >> 3, b = slot & 7;
            const float v = accP[st][b >> 1][b & 1] + xs[slot * 128 + tl];
            atomAddF(&out[(size_t)(b * S_ + s0 + st) * 256 + i], v);
        }
    }
}

extern "C" void kernel_launch(void* const* d_in, const int* in_sizes, int n_in,
                              void* d_out, int out_size, void* d_ws, size_t ws_size,
                              hipStream_t stream) {
    const float* x        = (const float*)d_in[0];
    const float* M        = (const float*)d_in[1];
    const float* P        = (const float*)d_in[2];
    const float* Wres     = (const float*)d_in[3];
    const float* ln_scale = (const float*)d_in[4];
    const float* ln_bias  = (const float*)d_in[5];
    const float* periods  = (const float*)d_in[6];

    float* out = (float*)d_out;
    char*  wsb = (char*)d_ws;
    const size_t MB = 1024 * 1024;
    float* y = (float*)wsb;                                     // 16 MiB
    unsigned short* Xb = (unsigned short*)(wsb + 16 * MB);      // 16 MiB
    unsigned short* Wb = (unsigned short*)(wsb + 32 * MB);      // 0.5 MiB

    const bool big  = (ws_size >= 39 * MB);        // un-aliased PTK at 33 MiB
    const bool mfma = (ws_size >= (size_t)34078720);

    float4* PTK;
    if (big) {
        PTK = (float4*)(wsb + 33 * MB);
        cvt_prep<<<4480, 256, 0, stream>>>(x, M, Wres, P, periods, Xb, Wb, PTK);
        dim3 ggrid(4, 256);
        gemm_mfma<<<ggrid, 256, 0, stream>>>(Xb, Wb, y, out);
    } else if (mfma) {
        PTK = (float4*)(wsb + 16 * MB);            // aliases Xb; written after gemm
        cvt_xw<<<4224, 256, 0, stream>>>(x, M, Wres, Xb, Wb);
        dim3 ggrid(4, 256);
        gemm_mfma<<<ggrid, 256, 0, stream>>>(Xb, Wb, y, out);
        prep_ptk<<<256, 256, 0, stream>>>(P, periods, PTK);
    } else {
        PTK = (float4*)(wsb + 16 * MB);
        dim3 ggrid(4, 128);
        gemm_kernel<<<ggrid, 256, 0, stream>>>(x, M, Wres, y, out);
        prep_ptk<<<256, 256, 0, stream>>>(P, periods, PTK);
    }

    ln_kernel<<<4096, 256, 0, stream>>>(y, ln_scale, ln_bias);

    cosnk_pk<<<1024, 256, 0, stream>>>(PTK, y, out);
}